// Round 5
// baseline (127.807 us; speedup 1.0000x reference)
//
#include <hip/hip_runtime.h>
#include <hip/hip_bf16.h>

#define NN 64
#define CC 512
#define MM 1600
#define KK 64
#define EPSF 1e-12f

typedef __attribute__((ext_vector_type(4))) float f32x4;
typedef __attribute__((ext_vector_type(8))) short bf16x8;

__device__ inline unsigned short f2bf(float f) {
    unsigned int u = __float_as_uint(f);
    unsigned int r = u + 0x7fffu + ((u >> 16) & 1u);   // RNE
    return (unsigned short)(r >> 16);
}

// ---------------------------------------------------------------------------
// w -> bf16
// ---------------------------------------------------------------------------
__global__ __launch_bounds__(256) void wconv_kernel(
    const float* __restrict__ w, unsigned short* __restrict__ wb)
{
    const int i = (blockIdx.x * 256 + threadIdx.x) * 8;
    float4 a = *(const float4*)(w + i);
    float4 b = *(const float4*)(w + i + 4);
    ushort4 u0, u1;
    u0.x = f2bf(a.x); u0.y = f2bf(a.y); u0.z = f2bf(a.z); u0.w = f2bf(a.w);
    u1.x = f2bf(b.x); u1.y = f2bf(b.y); u1.z = f2bf(b.z); u1.w = f2bf(b.w);
    *(ushort4*)(wb + i) = u0;
    *(ushort4*)(wb + i + 4) = u1;
}

// ---------------------------------------------------------------------------
// fused1: per (n, 64-m tile): x read straight from global (strided scalar f32,
// coalesced 64B segments), per-lane cvt->bf16 B-fragment, MFMA logits,
// per-lane sumsq -> rnorm via shfl, softmax over K, ap = a*rnorm bf16,
// asum partials. grid (25, 64), block 256.
// ---------------------------------------------------------------------------
__global__ __launch_bounds__(256) void fused1_kernel(
    const float* __restrict__ x, const unsigned short* __restrict__ wb,
    const float* __restrict__ bias,
    unsigned short* __restrict__ ap, float* __restrict__ asum_part)
{
    __shared__ float als[64][68];   // a (unscaled), [k][m]
    __shared__ float rn_s[64];

    const int t  = threadIdx.x;
    const int n  = blockIdx.y;
    const int mt = blockIdx.x;
    const int m0 = mt * 64;
    const int wv   = t >> 6;
    const int lane = t & 63;
    const int g    = lane >> 4;   // 0..3
    const int lr   = lane & 15;
    const int m_lane = m0 + wv * 16 + lr;

    f32x4 acc[4];
    #pragma unroll
    for (int kt = 0; kt < 4; ++kt) acc[kt] = (f32x4){0.f, 0.f, 0.f, 0.f};

    float ss = 0.f;
    const float* xcol = x + (size_t)n * CC * MM + m_lane;
    const unsigned short* wrow = wb + g * 8;

    #pragma unroll 2
    for (int cs = 0; cs < 16; ++cs) {
        const int cbase = cs * 32 + g * 8;
        float xv[8];
        #pragma unroll
        for (int j = 0; j < 8; ++j) xv[j] = xcol[(size_t)(cbase + j) * MM];
        bf16x8 bfrag;
        #pragma unroll
        for (int j = 0; j < 8; ++j) {
            ss += xv[j] * xv[j];
            bfrag[j] = (short)f2bf(xv[j]);
        }
        #pragma unroll
        for (int kt = 0; kt < 4; ++kt) {
            bf16x8 afrag = *(const bf16x8*)(wrow + (kt * 16 + lr) * CC + cs * 32);
            acc[kt] = __builtin_amdgcn_mfma_f32_16x16x32_bf16(afrag, bfrag, acc[kt], 0, 0, 0);
        }
    }

    // full sumsq for m_lane: reduce over the 4 g-slices
    ss += __shfl_xor(ss, 16);
    ss += __shfl_xor(ss, 32);
    const float rnm = 1.0f / fmaxf(sqrtf(ss), EPSF);
    if (g == 0) rn_s[wv * 16 + lr] = rnm;

    // lane holds k = kt*16 + g*4 + r for its m_lane; softmax over k
    float l[16];
    #pragma unroll
    for (int kt = 0; kt < 4; ++kt) {
        float4 bb = *(const float4*)(bias + kt * 16 + g * 4);
        l[kt * 4 + 0] = acc[kt][0] * rnm + bb.x;
        l[kt * 4 + 1] = acc[kt][1] * rnm + bb.y;
        l[kt * 4 + 2] = acc[kt][2] * rnm + bb.z;
        l[kt * 4 + 3] = acc[kt][3] * rnm + bb.w;
    }
    float mx = l[0];
    #pragma unroll
    for (int i = 1; i < 16; ++i) mx = fmaxf(mx, l[i]);
    mx = fmaxf(mx, __shfl_xor(mx, 16));
    mx = fmaxf(mx, __shfl_xor(mx, 32));
    float s = 0.f;
    #pragma unroll
    for (int i = 0; i < 16; ++i) { l[i] = __expf(l[i] - mx); s += l[i]; }
    s += __shfl_xor(s, 16);
    s += __shfl_xor(s, 32);
    const float inv = 1.0f / s;
    #pragma unroll
    for (int kt = 0; kt < 4; ++kt)
        #pragma unroll
        for (int r = 0; r < 4; ++r)
            als[kt * 16 + g * 4 + r][wv * 16 + lr] = l[kt * 4 + r] * inv;
    __syncthreads();

    // write a' = a*rnorm (bf16) row-wise + asum partial (plain store)
    {
        const int k = t >> 2, q = t & 3;
        float spart = 0.f;
        unsigned short ub[16];
        #pragma unroll
        for (int i = 0; i < 16; ++i) {
            float a = als[k][q * 16 + i];
            spart += a;
            ub[i] = f2bf(a * rn_s[q * 16 + i]);
        }
        unsigned short* dst = ap + ((size_t)(n * KK + k)) * MM + m0 + q * 16;
        *(uint4*)dst = *(uint4*)&ub[0];
        *(uint4*)(dst + 8) = *(uint4*)&ub[8];
        spart += __shfl_xor(spart, 1);
        spart += __shfl_xor(spart, 2);
        if (q == 0) asum_part[((size_t)(n * 25 + mt)) * 64 + k] = spart;
    }
}

// ---------------------------------------------------------------------------
// agg: D[k=64][c16 per wave] = sum_m a'[k][m] * x_bf16[c][m].
// x staged per 64c x 64m chunk through XOR-swizzled LDS (coalesced f32 loads,
// conflict-free ds_read_b128 fragments). m split in 2 halves (partial bufs).
// grid (8 c-tiles, 2 m-halves, 64 n), block 256. Plain stores.
// ---------------------------------------------------------------------------
__global__ __launch_bounds__(256) void aggm_kernel(
    const float* __restrict__ x, const unsigned short* __restrict__ ap,
    float* __restrict__ aggp)
{
    __shared__ __attribute__((aligned(16))) unsigned short als2[64][72];
    __shared__ __attribute__((aligned(16))) unsigned short xs[4096];
    const int t    = threadIdx.x;
    const int ct   = blockIdx.x;   // 0..7
    const int mh   = blockIdx.y;   // 0..1
    const int n    = blockIdx.z;
    const int wv   = t >> 6;
    const int lane = t & 63;
    const int g    = lane >> 4;
    const int lr   = lane & 15;

    f32x4 acc[4];
    #pragma unroll
    for (int kt = 0; kt < 4; ++kt) acc[kt] = (f32x4){0.f, 0.f, 0.f, 0.f};

    const int ks = t >> 2, qs = t & 3;   // ap staging coords
    const int sc = t >> 4, sm4 = t & 15; // x staging coords
    const int mc_beg = mh ? 13 : 0;
    const int mc_end = mh ? 25 : 13;

    for (int mc = mc_beg; mc < mc_end; ++mc) {
        const int m0 = mc * 64;
        __syncthreads();
        {   // stage ap chunk [64k][64m]
            const unsigned short* src = ap + ((size_t)(n * KK + ks)) * MM + m0 + qs * 16;
            uint4 w0 = *(const uint4*)src;
            uint4 w1 = *(const uint4*)(src + 8);
            *(uint4*)&als2[ks][qs * 16] = w0;
            *(uint4*)&als2[ks][qs * 16 + 8] = w1;
        }
        // stage x chunk [64c][64m] -> bf16, XOR-swizzled
        #pragma unroll
        for (int p = 0; p < 4; ++p) {
            const int c = p * 16 + sc;
            float4 v = *(const float4*)(x + ((size_t)(n * CC + ct * 64 + c)) * MM + m0 + sm4 * 4);
            ushort4 b;
            b.x = f2bf(v.x); b.y = f2bf(v.y); b.z = f2bf(v.z); b.w = f2bf(v.w);
            *(ushort4*)&xs[(c * 64 + sm4 * 4) ^ ((c & 7) << 3)] = b;
        }
        __syncthreads();
        #pragma unroll
        for (int msi = 0; msi < 2; ++msi) {
            const int ms = msi * 32;
            const int cl = wv * 16 + lr;
            bf16x8 bf = *(const bf16x8*)&xs[(cl * 64 + ms + g * 8) ^ ((cl & 7) << 3)];
            #pragma unroll
            for (int kt = 0; kt < 4; ++kt) {
                bf16x8 af = *(const bf16x8*)&als2[kt * 16 + lr][ms + g * 8];
                acc[kt] = __builtin_amdgcn_mfma_f32_16x16x32_bf16(af, bf, acc[kt], 0, 0, 0);
            }
        }
    }
    const int c_out = ct * 64 + wv * 16 + lr;
    #pragma unroll
    for (int kt = 0; kt < 4; ++kt)
        #pragma unroll
        for (int r = 0; r < 4; ++r) {
            const int k = kt * 16 + g * 4 + r;
            aggp[((size_t)((mh * NN + n) * KK + k)) * CC + c_out] = acc[kt][r];
        }
}

// ---------------------------------------------------------------------------
// vlad = (agg0+agg1) - asum*cent, intra-normalize over C; gns partial per (n,k)
// ---------------------------------------------------------------------------
__global__ __launch_bounds__(256) void vlad_kernel(
    const float* __restrict__ aggp, const float* __restrict__ asum_part,
    const float* __restrict__ cent, float* __restrict__ out,
    float* __restrict__ gns_part)
{
    __shared__ float wsum[4];
    __shared__ float sinv;
    const int nk = blockIdx.x;          // n*64 + k
    const int n = nk >> 6, k = nk & 63;
    const int t = threadIdx.x;
    const int u = t & 63;
    const size_t half = (size_t)NN * KK * CC;

    // reduce asum over 25 m-tile partials (each wave redundantly)
    float pa = (u < 25) ? asum_part[((size_t)(n * 25 + u)) * 64 + k] : 0.f;
    #pragma unroll
    for (int o = 32; o > 0; o >>= 1) pa += __shfl_xor(pa, o);
    const float s = pa;

    float2 a0 = *(const float2*)(aggp + (size_t)nk * CC + 2 * t);
    float2 a1 = *(const float2*)(aggp + half + (size_t)nk * CC + 2 * t);
    float2 cv = *(const float2*)(cent + (size_t)k * CC + 2 * t);
    float v0 = (a0.x + a1.x) - s * cv.x;
    float v1 = (a0.y + a1.y) - s * cv.y;
    float ss = v0 * v0 + v1 * v1;
    #pragma unroll
    for (int o = 32; o > 0; o >>= 1) ss += __shfl_down(ss, o);
    int wid = t >> 6;
    if (u == 0) wsum[wid] = ss;
    __syncthreads();
    if (t == 0) {
        float tot = wsum[0] + wsum[1] + wsum[2] + wsum[3];
        float inv = 1.0f / fmaxf(sqrtf(tot), EPSF);
        sinv = inv;
        gns_part[nk] = tot * inv * inv;
    }
    __syncthreads();
    float inv = sinv;
    float2 o2; o2.x = v0 * inv; o2.y = v1 * inv;
    *(float2*)(out + (size_t)nk * CC + 2 * t) = o2;
}

// ---------------------------------------------------------------------------
// global L2 scale per n (reduce 64 gns partials per wave, redundantly)
// ---------------------------------------------------------------------------
__global__ __launch_bounds__(256) void gscale_kernel(
    float* __restrict__ out, const float* __restrict__ gns_part)
{
    const int idx = blockIdx.x * 256 + threadIdx.x;   // float4 index
    const int n = blockIdx.x >> 5;                    // 32 blocks per n
    const int u = threadIdx.x & 63;
    float g = gns_part[n * 64 + u];
    #pragma unroll
    for (int o = 32; o > 0; o >>= 1) g += __shfl_xor(g, o);
    float inv = 1.0f / fmaxf(sqrtf(g), EPSF);
    float4 v = *(float4*)(out + (size_t)idx * 4);
    v.x *= inv; v.y *= inv; v.z *= inv; v.w *= inv;
    *(float4*)(out + (size_t)idx * 4) = v;
}

extern "C" void kernel_launch(void* const* d_in, const int* in_sizes, int n_in,
                              void* d_out, int out_size, void* d_ws, size_t ws_size,
                              hipStream_t stream)
{
    const float* x    = (const float*)d_in[0];
    const float* w    = (const float*)d_in[1];
    const float* bias = (const float*)d_in[2];
    const float* cent = (const float*)d_in[3];
    float* out = (float*)d_out;

    char* ws = (char*)d_ws;
    size_t off = 0;
    unsigned short* ap  = (unsigned short*)(ws + off); off += (size_t)NN * KK * MM * 2;
    unsigned short* wb  = (unsigned short*)(ws + off); off += (size_t)KK * CC * 2;
    float* aggp      = (float*)(ws + off); off += (size_t)2 * NN * KK * CC * 4;
    float* asum_part = (float*)(ws + off); off += (size_t)NN * 25 * KK * 4;
    float* gns_part  = (float*)(ws + off); off += (size_t)NN * KK * 4;

    wconv_kernel <<<16, 256, 0, stream>>>(w, wb);
    fused1_kernel<<<dim3(25, 64), 256, 0, stream>>>(x, wb, bias, ap, asum_part);
    aggm_kernel  <<<dim3(8, 2, 64), 256, 0, stream>>>(x, ap, aggp);
    vlad_kernel  <<<NN * KK, 256, 0, stream>>>(aggp, asum_part, cent, out, gns_part);
    gscale_kernel<<<(out_size / 4 + 255) / 256, 256, 0, stream>>>(out, gns_part);
}